// Round 1
// baseline (1148.694 us; speedup 1.0000x reference)
//
#include <hip/hip_runtime.h>
#include <math.h>

#define DIM 4096
#define NH 32
#define NKV 8
#define HD 128
#define BT 256           // B*T
#define SEQ 8192
#define NEWBASE 8176     // SEQ - T
#define QPAIRS (BT * NH * 64)   // 524288
#define KPAIRS (BT * NKV * 64)  // 131072

typedef short s16x4 __attribute__((ext_vector_type(4)));
typedef short s16x8 __attribute__((ext_vector_type(8)));
typedef float f32x4 __attribute__((ext_vector_type(4)));

__device__ __forceinline__ short f2bf(float f) {
  unsigned u = __float_as_uint(f);
  u += 0x7FFFu + ((u >> 16) & 1u);   // RNE
  return (short)(u >> 16);
}

__device__ __forceinline__ f32x4 mfma16(s16x8 a, s16x8 b, f32x4 c) {
  return __builtin_amdgcn_mfma_f32_16x16x32_bf16(a, b, c, 0, 0, 0);
}

// ---------------- RoPE tables (fp64, tiny) ----------------
__global__ void rope_table(const int* __restrict__ ipos,
                           float* __restrict__ ctab, float* __restrict__ stab) {
  int i = threadIdx.x;             // 1024 threads: t*64 + f
  int t = i >> 6, f = i & 63;
  double inv = exp(-((double)(2 * f) / 128.0) * log(500000.0));
  double ang = (double)ipos[t] * inv;
  ctab[i] = (float)cos(ang);
  stab[i] = (float)sin(ang);
}

// ---------------- generic C[m][n] = sum_k A[m][k]*B[n][k] (bf16 MFMA) -------
__device__ __forceinline__
void gemm_body(const float* __restrict__ A, const float* __restrict__ B,
               float* __restrict__ C, int K, int ldc, int bm, int bn) {
  __shared__ short As[128 * 40];
  __shared__ short Bs[128 * 40];
  const int tid = threadIdx.x;
  const int lane = tid & 63, w = tid >> 6;
  const int wm = w >> 1, wn = w & 1;
  const int l15 = lane & 15, l4 = lane >> 4;
  f32x4 acc[4][4] = {};
  const int nk = K >> 5;
  for (int kc = 0; kc < nk; ++kc) {
    __syncthreads();
#pragma unroll
    for (int i = 0; i < 4; ++i) {
      int id = tid + i * 256;
      int r = id >> 3, k4 = (id & 7) << 2;
      float4 va = *(const float4*)(A + (size_t)(bm * 128 + r) * K + (kc << 5) + k4);
      s16x4 ha = { f2bf(va.x), f2bf(va.y), f2bf(va.z), f2bf(va.w) };
      *(s16x4*)&As[r * 40 + k4] = ha;
      float4 vb = *(const float4*)(B + (size_t)(bn * 128 + r) * K + (kc << 5) + k4);
      s16x4 hb = { f2bf(vb.x), f2bf(vb.y), f2bf(vb.z), f2bf(vb.w) };
      *(s16x4*)&Bs[r * 40 + k4] = hb;
    }
    __syncthreads();
    s16x8 af[4], bfr[4];
#pragma unroll
    for (int m = 0; m < 4; ++m)
      af[m] = *(const s16x8*)&As[(wm * 64 + m * 16 + l15) * 40 + l4 * 8];
#pragma unroll
    for (int n = 0; n < 4; ++n)
      bfr[n] = *(const s16x8*)&Bs[(wn * 64 + n * 16 + l15) * 40 + l4 * 8];
#pragma unroll
    for (int m = 0; m < 4; ++m)
#pragma unroll
      for (int n = 0; n < 4; ++n)
        acc[m][n] = mfma16(af[m], bfr[n], acc[m][n]);
  }
#pragma unroll
  for (int m = 0; m < 4; ++m)
#pragma unroll
    for (int n = 0; n < 4; ++n)
#pragma unroll
      for (int r = 0; r < 4; ++r) {
        int row = bm * 128 + wm * 64 + m * 16 + l4 * 4 + r;
        int col = bn * 128 + wn * 64 + n * 16 + l15;
        C[(size_t)row * ldc + col] = acc[m][n][r];
      }
}

// fused QKV projection: grid (48, 2); bn 0..31 -> q, 32..39 -> k, 40..47 -> v
__global__ __launch_bounds__(256)
void gemm_qkv(const float* __restrict__ x,
              const float* __restrict__ wq, const float* __restrict__ wk,
              const float* __restrict__ wv,
              float* __restrict__ qb, float* __restrict__ kb, float* __restrict__ vb) {
  int bn = blockIdx.x;
  const float* Bw; float* Cp; int ldc;
  if (bn < 32)      { Bw = wq; Cp = qb; ldc = 4096; }
  else if (bn < 40) { Bw = wk; Cp = kb; ldc = 1024; bn -= 32; }
  else              { Bw = wv; Cp = vb; ldc = 1024; bn -= 40; }
  gemm_body(x, Bw, Cp, 4096, ldc, blockIdx.y, bn);
}

// out projection: grid (32, 2)
__global__ __launch_bounds__(256)
void gemm_out(const float* __restrict__ y, const float* __restrict__ wo,
              float* __restrict__ out) {
  gemm_body(y, wo, out, 4096, 4096, blockIdx.y, blockIdx.x);
}

// ---------------- RoPE apply (in-place on ws q and k_new) ----------------
__global__ __launch_bounds__(256)
void rope_apply(float* __restrict__ q, float* __restrict__ k,
                const float* __restrict__ ctab, const float* __restrict__ stab) {
  int idx = blockIdx.x * 256 + threadIdx.x;
  float* p; int t, f;
  if (idx < QPAIRS) {
    int m = idx >> 11;              // 32 heads * 64 pairs per row
    int rem = idx & 2047;
    f = rem & 63;
    t = m & 15;
    p = q + (size_t)m * 4096 + (rem >> 6) * 128 + 2 * f;
  } else {
    int id2 = idx - QPAIRS;
    int m = id2 >> 9;               // 8 heads * 64 pairs per row
    int rem = id2 & 511;
    f = rem & 63;
    t = m & 15;
    p = k + (size_t)m * 1024 + (rem >> 6) * 128 + 2 * f;
  }
  float c = ctab[t * 64 + f], s = stab[t * 64 + f];
  float x0 = p[0], x1 = p[1];
  p[0] = x0 * c - x1 * s;
  p[1] = x0 * s + x1 * c;
}

// ---------------- flash attention over one (b, g, s-half) ----------------
// 4 waves; wave w owns q-rows [w*16, w*16+16) where qr = t*4 + rep.
__global__ __launch_bounds__(256)
void attn(const float* __restrict__ kc_, const float* __restrict__ vc_,
          const float* __restrict__ qb, const float* __restrict__ kn,
          const float* __restrict__ vn, const int* __restrict__ ipos,
          float* __restrict__ pO, float* __restrict__ pM, float* __restrict__ pL) {
  __shared__ short Ks[128 * 128];   // [s][d], XOR-swizzled; P aliases front
  __shared__ short Vs[128 * 128];   // [d][s], XOR-swizzled
  const int sh = blockIdx.x, g = blockIdx.y, b = blockIdx.z;
  const int tid = threadIdx.x, lane = tid & 63, w = tid >> 6;
  const int l15 = lane & 15, l4 = lane >> 4;
  const float scale = 0.08838834764831845f;  // 1/sqrt(128)

  // Q fragments (A-layout: row = l15, k = l4*8 + j, per 32-k step)
  s16x8 qa[4];
  {
    int qr = w * 16 + l15;
    int t = qr >> 2, r = qr & 3, h = g * 4 + r;
    const float* qp = qb + (size_t)(b * 16 + t) * 4096 + h * 128;
#pragma unroll
    for (int ks = 0; ks < 4; ++ks) {
      float4 v0 = *(const float4*)(qp + ks * 32 + l4 * 8);
      float4 v1 = *(const float4*)(qp + ks * 32 + l4 * 8 + 4);
      qa[ks] = s16x8{ f2bf(v0.x), f2bf(v0.y), f2bf(v0.z), f2bf(v0.w),
                      f2bf(v1.x), f2bf(v1.y), f2bf(v1.z), f2bf(v1.w) };
    }
  }
  int ip[4];
#pragma unroll
  for (int r = 0; r < 4; ++r) ip[r] = ipos[(w * 16 + l4 * 4 + r) >> 2];

  f32x4 o[8] = {};
  float mrun[4] = { -1e30f, -1e30f, -1e30f, -1e30f };
  float lrun[4] = { 0.f, 0.f, 0.f, 0.f };

  for (int cs = 0; cs < 32; ++cs) {
    const int base = sh * 4096 + cs * 128;
    __syncthreads();                     // prev chunk fully consumed
    // ---- stage K: [s][d] bf16, swizzle d ^= (s&7)<<3 ----
#pragma unroll
    for (int i = 0; i < 16; ++i) {
      int id = tid + i * 256;            // 0..4095
      int s = id >> 5, d4 = (id & 31) << 2;
      int sg = base + s;
      const float* src = (sg >= NEWBASE)
          ? (kn + (size_t)(b * 16 + (sg - NEWBASE)) * 1024 + g * 128 + d4)
          : (kc_ + ((size_t)b * SEQ + sg) * 1024 + g * 128 + d4);
      float4 v = *(const float4*)src;
      s16x4 hv = { f2bf(v.x), f2bf(v.y), f2bf(v.z), f2bf(v.w) };
      *(s16x4*)&Ks[s * 128 + (d4 ^ ((s & 7) << 3))] = hv;
    }
    // ---- stage V transposed: [d][s] bf16, swizzle s ^= (d&7)<<3 ----
#pragma unroll
    for (int i = 0; i < 16; ++i) {
      int id = tid + i * 256;
      int d = id & 127, s0 = (id >> 7) << 2;
      short tv[4];
#pragma unroll
      for (int j = 0; j < 4; ++j) {
        int sg = base + s0 + j;
        const float* src = (sg >= NEWBASE)
            ? (vn + (size_t)(b * 16 + (sg - NEWBASE)) * 1024 + g * 128 + d)
            : (vc_ + ((size_t)b * SEQ + sg) * 1024 + g * 128 + d);
        tv[j] = f2bf(*src);
      }
      s16x4 hv = { tv[0], tv[1], tv[2], tv[3] };
      *(s16x4*)&Vs[d * 128 + (s0 ^ ((d & 7) << 3))] = hv;
    }
    __syncthreads();
    // ---- QK^T : sc[nf] covers rows(16) x s-cols nf*16+l15 ----
    f32x4 sc[8] = {};
#pragma unroll
    for (int ks = 0; ks < 4; ++ks) {
      int dd = ks * 32 + l4 * 8;
#pragma unroll
      for (int nf = 0; nf < 8; ++nf) {
        int s = nf * 16 + l15;
        s16x8 kb = *(const s16x8*)&Ks[s * 128 + (dd ^ ((s & 7) << 3))];
        sc[nf] = mfma16(qa[ks], kb, sc[nf]);
      }
    }
    // ---- online softmax (registers) ----
    float cmax[4] = { -1e30f, -1e30f, -1e30f, -1e30f };
#pragma unroll
    for (int nf = 0; nf < 8; ++nf) {
      int sg = base + nf * 16 + l15;
#pragma unroll
      for (int r = 0; r < 4; ++r) {
        float v = sc[nf][r] * scale;
        v = (sg <= ip[r]) ? v : -1e30f;
        sc[nf][r] = v;
        cmax[r] = fmaxf(cmax[r], v);
      }
    }
    float cfv[4];
#pragma unroll
    for (int r = 0; r < 4; ++r) {
      cmax[r] = fmaxf(cmax[r], __shfl_xor(cmax[r], 1, 64));
      cmax[r] = fmaxf(cmax[r], __shfl_xor(cmax[r], 2, 64));
      cmax[r] = fmaxf(cmax[r], __shfl_xor(cmax[r], 4, 64));
      cmax[r] = fmaxf(cmax[r], __shfl_xor(cmax[r], 8, 64));
      float mn = fmaxf(mrun[r], cmax[r]);
      cfv[r] = __expf(mrun[r] - mn);
      mrun[r] = mn;
    }
    __syncthreads();                     // all waves done reading Ks
    // ---- P = exp(s - m) -> bf16 into LDS (aliases Ks), rowsum ----
    short* Pw = &Ks[w * (16 * 136)];
    float rsum[4] = { 0.f, 0.f, 0.f, 0.f };
#pragma unroll
    for (int nf = 0; nf < 8; ++nf) {
#pragma unroll
      for (int r = 0; r < 4; ++r) {
        float p = __expf(sc[nf][r] - mrun[r]);
        rsum[r] += p;
        Pw[(l4 * 4 + r) * 136 + nf * 16 + l15] = f2bf(p);
      }
    }
#pragma unroll
    for (int r = 0; r < 4; ++r) {
      rsum[r] += __shfl_xor(rsum[r], 1, 64);
      rsum[r] += __shfl_xor(rsum[r], 2, 64);
      rsum[r] += __shfl_xor(rsum[r], 4, 64);
      rsum[r] += __shfl_xor(rsum[r], 8, 64);
      lrun[r] = lrun[r] * cfv[r] + rsum[r];
    }
#pragma unroll
    for (int nd = 0; nd < 8; ++nd)
#pragma unroll
      for (int r = 0; r < 4; ++r) o[nd][r] *= cfv[r];
    // ---- PV ----
#pragma unroll
    for (int ks = 0; ks < 4; ++ks) {
      s16x8 pa = *(const s16x8*)&Pw[l15 * 136 + ks * 32 + l4 * 8];
#pragma unroll
      for (int nd = 0; nd < 8; ++nd) {
        int d = nd * 16 + l15;
        int s = ks * 32 + l4 * 8;
        s16x8 vb = *(const s16x8*)&Vs[d * 128 + (s ^ ((d & 7) << 3))];
        o[nd] = mfma16(pa, vb, o[nd]);
      }
    }
  }
  // ---- write partials ----
  const int blk = (b * 8 + g) * 2 + sh;
  float* Ob = pO + (size_t)blk * 64 * 128;
#pragma unroll
  for (int nd = 0; nd < 8; ++nd)
#pragma unroll
    for (int r = 0; r < 4; ++r)
      Ob[(w * 16 + l4 * 4 + r) * 128 + nd * 16 + l15] = o[nd][r];
  if (l15 == 0) {
#pragma unroll
    for (int r = 0; r < 4; ++r) {
      pM[blk * 64 + w * 16 + l4 * 4 + r] = mrun[r];
      pL[blk * 64 + w * 16 + l4 * 4 + r] = lrun[r];
    }
  }
}

// ---------------- merge the two s-halves, write y[b*16+t][h*128+d] ----------
__global__ __launch_bounds__(256)
void merge(const float* __restrict__ pO, const float* __restrict__ pM,
           const float* __restrict__ pL, float* __restrict__ y) {
  const int g = blockIdx.x, b = blockIdx.y;
  const int b0 = (b * 8 + g) * 2, b1 = b0 + 1;
#pragma unroll
  for (int i = 0; i < 32; ++i) {
    int id = threadIdx.x + i * 256;     // 0..8191
    int qr = id >> 7, d = id & 127;
    float m1 = pM[b0 * 64 + qr], m2 = pM[b1 * 64 + qr];
    float l1 = pL[b0 * 64 + qr], l2 = pL[b1 * 64 + qr];
    float mm = fmaxf(m1, m2);
    float a1 = __expf(m1 - mm), a2 = __expf(m2 - mm);
    float val = (pO[(size_t)b0 * 8192 + id] * a1 + pO[(size_t)b1 * 8192 + id] * a2)
              / (l1 * a1 + l2 * a2);
    int t = qr >> 2, r = qr & 3, h = g * 4 + r;
    y[(size_t)(b * 16 + t) * 4096 + h * 128 + d] = val;
  }
}

extern "C" void kernel_launch(void* const* d_in, const int* in_sizes, int n_in,
                              void* d_out, int out_size, void* d_ws, size_t ws_size,
                              hipStream_t stream) {
  const float* x      = (const float*)d_in[0];
  const int*   ipos   = (const int*)d_in[3];
  const float* kcache = (const float*)d_in[5];
  const float* vcache = (const float*)d_in[6];
  const float* wq     = (const float*)d_in[7];
  const float* wk     = (const float*)d_in[8];
  const float* wv     = (const float*)d_in[9];
  const float* wo     = (const float*)d_in[10];
  float* out = (float*)d_out;

  float* q_buf = (float*)d_ws;            // 1048576
  float* k_new = q_buf + 1048576;         // 262144
  float* v_new = k_new + 262144;          // 262144
  float* y_buf = v_new + 262144;          // 1048576
  float* ctab  = y_buf + 1048576;         // 1024
  float* stab  = ctab + 1024;             // 1024
  float* pO    = stab + 1024;             // 2097152
  float* pM    = pO + 2097152;            // 16384
  float* pL    = pM + 16384;              // 16384  (total ~18.1 MB)

  rope_table<<<1, 1024, 0, stream>>>(ipos, ctab, stab);
  gemm_qkv<<<dim3(48, 2), 256, 0, stream>>>(x, wq, wk, wv, q_buf, k_new, v_new);
  rope_apply<<<2560, 256, 0, stream>>>(q_buf, k_new, ctab, stab);
  attn<<<dim3(2, 8, 16), 256, 0, stream>>>(kcache, vcache, q_buf, k_new, v_new,
                                           ipos, pO, pM, pL);
  merge<<<dim3(8, 16), 256, 0, stream>>>(pO, pM, pL, y_buf);
  gemm_out<<<dim3(32, 2), 256, 0, stream>>>(y_buf, wo, out);
}

// Round 2
// 835.382 us; speedup vs baseline: 1.3751x; 1.3751x over previous
//
#include <hip/hip_runtime.h>
#include <math.h>

#define DIM 4096
#define SEQ 8192
#define NEWBASE 8176     // SEQ - T
#define CH 64            // attn chunk rows
#define QPAIRS (256 * 32 * 64)   // 524288

typedef short s16x4 __attribute__((ext_vector_type(4)));
typedef short s16x8 __attribute__((ext_vector_type(8)));
typedef float f32x4 __attribute__((ext_vector_type(4)));

__device__ __forceinline__ short f2bf(float f) {
  unsigned u = __float_as_uint(f);
  u += 0x7FFFu + ((u >> 16) & 1u);   // RNE
  return (short)(u >> 16);
}

__device__ __forceinline__ f32x4 mfma16(s16x8 a, s16x8 b, f32x4 c) {
  return __builtin_amdgcn_mfma_f32_16x16x32_bf16(a, b, c, 0, 0, 0);
}

// ---------------- RoPE tables (fp64, tiny) ----------------
__global__ void rope_table(const int* __restrict__ ipos,
                           float* __restrict__ ctab, float* __restrict__ stab) {
  int i = threadIdx.x;             // 1024 threads: t*64 + f
  int t = i >> 6, f = i & 63;
  double inv = exp(-((double)(2 * f) / 128.0) * log(500000.0));
  double ang = (double)ipos[t] * inv;
  ctab[i] = (float)cos(ang);
  stab[i] = (float)sin(ang);
}

// ---------------- generic C[m][n] = sum_k A[m][k]*B[n][k] (bf16 MFMA) -------
__device__ __forceinline__
void gemm_body(const float* __restrict__ A, const float* __restrict__ B,
               float* __restrict__ C, int K, int ldc, int bm, int bn) {
  __shared__ short As[128 * 40];
  __shared__ short Bs[128 * 40];
  const int tid = threadIdx.x;
  const int lane = tid & 63, w = tid >> 6;
  const int wm = w >> 1, wn = w & 1;
  const int l15 = lane & 15, l4 = lane >> 4;
  f32x4 acc[4][4] = {};
  const int nk = K >> 5;
  for (int kc = 0; kc < nk; ++kc) {
    __syncthreads();
#pragma unroll
    for (int i = 0; i < 4; ++i) {
      int id = tid + i * 256;
      int r = id >> 3, k4 = (id & 7) << 2;
      float4 va = *(const float4*)(A + (size_t)(bm * 128 + r) * K + (kc << 5) + k4);
      s16x4 ha = { f2bf(va.x), f2bf(va.y), f2bf(va.z), f2bf(va.w) };
      *(s16x4*)&As[r * 40 + k4] = ha;
      float4 vb = *(const float4*)(B + (size_t)(bn * 128 + r) * K + (kc << 5) + k4);
      s16x4 hb = { f2bf(vb.x), f2bf(vb.y), f2bf(vb.z), f2bf(vb.w) };
      *(s16x4*)&Bs[r * 40 + k4] = hb;
    }
    __syncthreads();
    s16x8 af[4], bfr[4];
#pragma unroll
    for (int m = 0; m < 4; ++m)
      af[m] = *(const s16x8*)&As[(wm * 64 + m * 16 + l15) * 40 + l4 * 8];
#pragma unroll
    for (int n = 0; n < 4; ++n)
      bfr[n] = *(const s16x8*)&Bs[(wn * 64 + n * 16 + l15) * 40 + l4 * 8];
#pragma unroll
    for (int m = 0; m < 4; ++m)
#pragma unroll
      for (int n = 0; n < 4; ++n)
        acc[m][n] = mfma16(af[m], bfr[n], acc[m][n]);
  }
#pragma unroll
  for (int m = 0; m < 4; ++m)
#pragma unroll
    for (int n = 0; n < 4; ++n)
#pragma unroll
      for (int r = 0; r < 4; ++r) {
        int row = bm * 128 + wm * 64 + m * 16 + l4 * 4 + r;
        int col = bn * 128 + wn * 64 + n * 16 + l15;
        C[(size_t)row * ldc + col] = acc[m][n][r];
      }
}

// fused QKV projection: grid (48, 2); bn 0..31 -> q, 32..39 -> k, 40..47 -> v
__global__ __launch_bounds__(256)
void gemm_qkv(const float* __restrict__ x,
              const float* __restrict__ wq, const float* __restrict__ wk,
              const float* __restrict__ wv,
              float* __restrict__ qb, float* __restrict__ kb, float* __restrict__ vb) {
  int bn = blockIdx.x;
  const float* Bw; float* Cp; int ldc;
  if (bn < 32)      { Bw = wq; Cp = qb; ldc = 4096; }
  else if (bn < 40) { Bw = wk; Cp = kb; ldc = 1024; bn -= 32; }
  else              { Bw = wv; Cp = vb; ldc = 1024; bn -= 40; }
  gemm_body(x, Bw, Cp, 4096, ldc, blockIdx.y, bn);
}

// out projection: grid (32, 2)
__global__ __launch_bounds__(256)
void gemm_out(const float* __restrict__ y, const float* __restrict__ wo,
              float* __restrict__ out) {
  gemm_body(y, wo, out, 4096, 4096, blockIdx.y, blockIdx.x);
}

// ---------------- RoPE apply (in-place on ws q and k_new) ----------------
__global__ __launch_bounds__(256)
void rope_apply(float* __restrict__ q, float* __restrict__ k,
                const float* __restrict__ ctab, const float* __restrict__ stab) {
  int idx = blockIdx.x * 256 + threadIdx.x;
  float* p; int t, f;
  if (idx < QPAIRS) {
    int m = idx >> 11;              // 32 heads * 64 pairs per row
    int rem = idx & 2047;
    f = rem & 63;
    t = m & 15;
    p = q + (size_t)m * 4096 + (rem >> 6) * 128 + 2 * f;
  } else {
    int id2 = idx - QPAIRS;
    int m = id2 >> 9;               // 8 heads * 64 pairs per row
    int rem = id2 & 511;
    f = rem & 63;
    t = m & 15;
    p = k + (size_t)m * 1024 + (rem >> 6) * 128 + 2 * f;
  }
  float c = ctab[t * 64 + f], s = stab[t * 64 + f];
  float x0 = p[0], x1 = p[1];
  p[0] = x0 * c - x1 * s;
  p[1] = x0 * s + x1 * c;
}

// ---------------- flash attention over one (b, g, s-split) ----------------
// 4 waves; wave w owns q-rows [w*16, w*16+16) where qr = t*4 + rep.
// grid (NS, 8, 16); 40 KB LDS -> 4 blocks/CU.
__global__ __launch_bounds__(256, 4)
void attn(const float* __restrict__ kc_, const float* __restrict__ vc_,
          const float* __restrict__ qb, const float* __restrict__ kn,
          const float* __restrict__ vn, const int* __restrict__ ipos,
          float* __restrict__ pO, float* __restrict__ pM, float* __restrict__ pL) {
  __shared__ short Ks[CH * 128];    // [s][d], swizzle d ^= (s&7)<<3
  __shared__ short Vs[128 * CH];    // [d][s], swizzle s ^= (d&7)<<3
  __shared__ short Ps[4 * 16 * CH]; // per-wave [q][s], swizzle s ^= (q&7)<<3
  const int NS = gridDim.x;
  const int schunks = (SEQ / CH) / NS;
  const int sh = blockIdx.x, g = blockIdx.y, b = blockIdx.z;
  const int tid = threadIdx.x, lane = tid & 63, w = tid >> 6;
  const int l15 = lane & 15, l4 = lane >> 4;
  const float scale = 0.08838834764831845f;  // 1/sqrt(128)

  const float* kc_b = kc_ + ((size_t)b * SEQ) * 1024 + g * 128;
  const float* vc_b = vc_ + ((size_t)b * SEQ) * 1024 + g * 128;
  const float* kn_b = kn + (size_t)b * 16 * 1024 + g * 128;
  const float* vn_b = vn + (size_t)b * 16 * 1024 + g * 128;

  // Q fragments (A-layout: row = l15, k = l4*8 + j, per 32-k step)
  s16x8 qa[4];
  {
    int qr = w * 16 + l15;
    int t = qr >> 2, r = qr & 3, h = g * 4 + r;
    const float* qp = qb + (size_t)(b * 16 + t) * 4096 + h * 128;
#pragma unroll
    for (int ks = 0; ks < 4; ++ks) {
      float4 v0 = *(const float4*)(qp + ks * 32 + l4 * 8);
      float4 v1 = *(const float4*)(qp + ks * 32 + l4 * 8 + 4);
      qa[ks] = s16x8{ f2bf(v0.x), f2bf(v0.y), f2bf(v0.z), f2bf(v0.w),
                      f2bf(v1.x), f2bf(v1.y), f2bf(v1.z), f2bf(v1.w) };
    }
  }
  int ip[4];
#pragma unroll
  for (int r = 0; r < 4; ++r) ip[r] = ipos[(w * 16 + l4 * 4 + r) >> 2];

  f32x4 o[8] = {};
  float mrun[4] = { -1e30f, -1e30f, -1e30f, -1e30f };
  float lrun[4] = { 0.f, 0.f, 0.f, 0.f };

  for (int cs = 0; cs < schunks; ++cs) {
    const int base = (sh * schunks + cs) * CH;
    __syncthreads();                     // prev chunk fully consumed
    if (base + CH <= NEWBASE) {
      // ---- pure-cache staging (hot path) ----
#pragma unroll
      for (int i = 0; i < 8; ++i) {
        int id = tid + i * 256;          // 0..2047
        int s = id >> 5, d4 = (id & 31) << 2;
        float4 v = *(const float4*)(kc_b + (size_t)(base + s) * 1024 + d4);
        s16x4 hv = { f2bf(v.x), f2bf(v.y), f2bf(v.z), f2bf(v.w) };
        *(s16x4*)&Ks[s * 128 + (d4 ^ ((s & 7) << 3))] = hv;
      }
#pragma unroll
      for (int i = 0; i < 8; ++i) {
        int id = tid + i * 256;
        int d = id & 127, s0 = (id >> 7) << 2;
        const float* vp = vc_b + (size_t)(base + s0) * 1024 + d;
        s16x4 hv = { f2bf(vp[0]), f2bf(vp[1024]), f2bf(vp[2048]), f2bf(vp[3072]) };
        *(s16x4*)&Vs[d * CH + (s0 ^ ((d & 7) << 3))] = hv;
      }
    } else {
      // ---- tail chunk: mixes cache and new rows ----
#pragma unroll
      for (int i = 0; i < 8; ++i) {
        int id = tid + i * 256;
        int s = id >> 5, d4 = (id & 31) << 2;
        int sg = base + s;
        const float* src = (sg >= NEWBASE)
            ? (kn_b + (size_t)(sg - NEWBASE) * 1024 + d4)
            : (kc_b + (size_t)sg * 1024 + d4);
        float4 v = *(const float4*)src;
        s16x4 hv = { f2bf(v.x), f2bf(v.y), f2bf(v.z), f2bf(v.w) };
        *(s16x4*)&Ks[s * 128 + (d4 ^ ((s & 7) << 3))] = hv;
      }
#pragma unroll
      for (int i = 0; i < 8; ++i) {
        int id = tid + i * 256;
        int d = id & 127, s0 = (id >> 7) << 2;
        short tv[4];
#pragma unroll
        for (int j = 0; j < 4; ++j) {
          int sg = base + s0 + j;
          const float* src = (sg >= NEWBASE)
              ? (vn_b + (size_t)(sg - NEWBASE) * 1024 + d)
              : (vc_b + (size_t)sg * 1024 + d);
          tv[j] = f2bf(*src);
        }
        s16x4 hv = { tv[0], tv[1], tv[2], tv[3] };
        *(s16x4*)&Vs[d * CH + (s0 ^ ((d & 7) << 3))] = hv;
      }
    }
    __syncthreads();
    // ---- QK^T : sc[nf] covers rows(16) x s-cols nf*16+l15 ----
    f32x4 sc[4] = {};
#pragma unroll
    for (int ks = 0; ks < 4; ++ks) {
      int dd = ks * 32 + l4 * 8;
#pragma unroll
      for (int nf = 0; nf < 4; ++nf) {
        int s = nf * 16 + l15;
        s16x8 kb = *(const s16x8*)&Ks[s * 128 + (dd ^ ((s & 7) << 3))];
        sc[nf] = mfma16(qa[ks], kb, sc[nf]);
      }
    }
    // ---- online softmax (registers) ----
    float cmax[4] = { -1e30f, -1e30f, -1e30f, -1e30f };
#pragma unroll
    for (int nf = 0; nf < 4; ++nf) {
      int sg = base + nf * 16 + l15;
#pragma unroll
      for (int r = 0; r < 4; ++r) {
        float v = sc[nf][r] * scale;
        v = (sg <= ip[r]) ? v : -1e30f;
        sc[nf][r] = v;
        cmax[r] = fmaxf(cmax[r], v);
      }
    }
    float cfv[4];
#pragma unroll
    for (int r = 0; r < 4; ++r) {
      cmax[r] = fmaxf(cmax[r], __shfl_xor(cmax[r], 1, 64));
      cmax[r] = fmaxf(cmax[r], __shfl_xor(cmax[r], 2, 64));
      cmax[r] = fmaxf(cmax[r], __shfl_xor(cmax[r], 4, 64));
      cmax[r] = fmaxf(cmax[r], __shfl_xor(cmax[r], 8, 64));
      float mn = fmaxf(mrun[r], cmax[r]);
      cfv[r] = __expf(mrun[r] - mn);
      mrun[r] = mn;
    }
    // ---- P = exp(s - m) -> bf16 into per-wave Ps region, rowsum ----
    short* Pw = &Ps[w * (16 * CH)];
    float rsum[4] = { 0.f, 0.f, 0.f, 0.f };
#pragma unroll
    for (int nf = 0; nf < 4; ++nf) {
#pragma unroll
      for (int r = 0; r < 4; ++r) {
        float p = __expf(sc[nf][r] - mrun[r]);
        rsum[r] += p;
        int row = l4 * 4 + r;
        Pw[row * CH + ((nf * 16 + l15) ^ ((row & 7) << 3))] = f2bf(p);
      }
    }
#pragma unroll
    for (int r = 0; r < 4; ++r) {
      rsum[r] += __shfl_xor(rsum[r], 1, 64);
      rsum[r] += __shfl_xor(rsum[r], 2, 64);
      rsum[r] += __shfl_xor(rsum[r], 4, 64);
      rsum[r] += __shfl_xor(rsum[r], 8, 64);
      lrun[r] = lrun[r] * cfv[r] + rsum[r];
    }
#pragma unroll
    for (int nd = 0; nd < 8; ++nd)
#pragma unroll
      for (int r = 0; r < 4; ++r) o[nd][r] *= cfv[r];
    // ---- PV (reads own wave's P + shared Vs) ----
#pragma unroll
    for (int ks = 0; ks < 2; ++ks) {
      int ss = ks * 32 + l4 * 8;
      s16x8 pa = *(const s16x8*)&Pw[l15 * CH + (ss ^ ((l15 & 7) << 3))];
#pragma unroll
      for (int nd = 0; nd < 8; ++nd) {
        int d = nd * 16 + l15;
        s16x8 vb = *(const s16x8*)&Vs[d * CH + (ss ^ ((d & 7) << 3))];
        o[nd] = mfma16(pa, vb, o[nd]);
      }
    }
  }
  // ---- write partials ----
  const int blk = (b * 8 + g) * NS + sh;
  float* Ob = pO + (size_t)blk * 64 * 128;
#pragma unroll
  for (int nd = 0; nd < 8; ++nd)
#pragma unroll
    for (int r = 0; r < 4; ++r)
      Ob[(w * 16 + l4 * 4 + r) * 128 + nd * 16 + l15] = o[nd][r];
  if (l15 == 0) {
#pragma unroll
    for (int r = 0; r < 4; ++r) {
      pM[blk * 64 + w * 16 + l4 * 4 + r] = mrun[r];
      pL[blk * 64 + w * 16 + l4 * 4 + r] = lrun[r];
    }
  }
}

// ---------------- merge the NS s-splits, write y[b*16+t][h*128+d] ----------
__global__ __launch_bounds__(256)
void merge(const float* __restrict__ pO, const float* __restrict__ pM,
           const float* __restrict__ pL, float* __restrict__ y, int NS) {
  const int g = blockIdx.x, b = blockIdx.y;
  const int bb = (b * 8 + g) * NS;
#pragma unroll 4
  for (int i = 0; i < 32; ++i) {
    int id = threadIdx.x + i * 256;     // 0..8191
    int qr = id >> 7, d = id & 127;
    float M = -1e30f;
    for (int p = 0; p < NS; ++p) M = fmaxf(M, pM[(bb + p) * 64 + qr]);
    float acc = 0.f, den = 0.f;
    for (int p = 0; p < NS; ++p) {
      float a = __expf(pM[(bb + p) * 64 + qr] - M);
      acc += pO[(size_t)(bb + p) * 8192 + id] * a;
      den += pL[(bb + p) * 64 + qr] * a;
    }
    int t = qr >> 2, r = qr & 3, h = g * 4 + r;
    y[(size_t)(b * 16 + t) * 4096 + h * 128 + d] = acc / den;
  }
}

extern "C" void kernel_launch(void* const* d_in, const int* in_sizes, int n_in,
                              void* d_out, int out_size, void* d_ws, size_t ws_size,
                              hipStream_t stream) {
  const float* x      = (const float*)d_in[0];
  const int*   ipos   = (const int*)d_in[3];
  const float* kcache = (const float*)d_in[5];
  const float* vcache = (const float*)d_in[6];
  const float* wq     = (const float*)d_in[7];
  const float* wk     = (const float*)d_in[8];
  const float* wv     = (const float*)d_in[9];
  const float* wo     = (const float*)d_in[10];
  float* out = (float*)d_out;

  int NS = 8;
  size_t fixed_f = 1048576 + 262144 + 262144 + 1048576 + 2048;  // q,kn,vn,y,tabs
  size_t need8 = (fixed_f + (size_t)128 * NS * 64 * 128 + 2 * (size_t)128 * NS * 64) * 4;
  if (ws_size < need8) NS = 2;

  float* q_buf = (float*)d_ws;            // 1048576
  float* k_new = q_buf + 1048576;         // 262144
  float* v_new = k_new + 262144;          // 262144
  float* y_buf = v_new + 262144;          // 1048576
  float* ctab  = y_buf + 1048576;         // 1024
  float* stab  = ctab + 1024;             // 1024
  float* pO    = stab + 1024;             // 128*NS*8192
  float* pM    = pO + (size_t)128 * NS * 8192;
  float* pL    = pM + (size_t)128 * NS * 64;

  rope_table<<<1, 1024, 0, stream>>>(ipos, ctab, stab);
  gemm_qkv<<<dim3(48, 2), 256, 0, stream>>>(x, wq, wk, wv, q_buf, k_new, v_new);
  rope_apply<<<2560, 256, 0, stream>>>(q_buf, k_new, ctab, stab);
  attn<<<dim3(NS, 8, 16), 256, 0, stream>>>(kcache, vcache, q_buf, k_new, v_new,
                                            ipos, pO, pM, pL);
  merge<<<dim3(8, 16), 256, 0, stream>>>(pO, pM, pL, y_buf, NS);
  gemm_out<<<dim3(32, 2), 256, 0, stream>>>(y_buf, wo, out);
}

// Round 3
// 490.388 us; speedup vs baseline: 2.3424x; 1.7035x over previous
//
#include <hip/hip_runtime.h>
#include <math.h>

#define SEQ 8192
#define NEWBASE 8176     // SEQ - T
#define CH 32            // attn chunk rows
#define NS 8             // attn s-splits

typedef short s16x4 __attribute__((ext_vector_type(4)));
typedef short s16x8 __attribute__((ext_vector_type(8)));
typedef float f32x4 __attribute__((ext_vector_type(4)));

__device__ __forceinline__ short f2bf(float f) {
  unsigned u = __float_as_uint(f);
  u += 0x7FFFu + ((u >> 16) & 1u);   // RNE
  return (short)(u >> 16);
}

__device__ __forceinline__ f32x4 mfma16(s16x8 a, s16x8 b, f32x4 c) {
  return __builtin_amdgcn_mfma_f32_16x16x32_bf16(a, b, c, 0, 0, 0);
}

// ---------------- RoPE tables (fp64, tiny) ----------------
__global__ void rope_table(const int* __restrict__ ipos,
                           float* __restrict__ ctab, float* __restrict__ stab) {
  int i = blockIdx.x * 64 + threadIdx.x;   // 1024 total: t*64 + f
  int t = i >> 6, f = i & 63;
  double inv = exp(-((double)(2 * f) / 128.0) * log(500000.0));
  double ang = (double)ipos[t] * inv;
  ctab[i] = (float)cos(ang);
  stab[i] = (float)sin(ang);
}

// ---- 64Mx128N tile GEMM w/ register-prefetch pipeline; C[m][n]=sum_k A[m][k]B[n][k]
template<int KSTEPS>
__device__ __forceinline__
void gemm_tile(const float* __restrict__ A, const float* __restrict__ Bw,
               float* __restrict__ Cp, int ldc) {
  __shared__ short As[64 * 72];
  __shared__ short Bs[128 * 72];
  const int tid = threadIdx.x, lane = tid & 63, w = tid >> 6;
  const int l15 = lane & 15, l4 = lane >> 4;
  f32x4 acc[8] = {};
  float4 ar[4], br[8];

  auto issue = [&](int st) {
    const float* Ab = A + st * 64;
    const float* Bb = Bw + st * 64;
#pragma unroll
    for (int i = 0; i < 4; ++i) {
      int id = tid + i * 256;
      ar[i] = *(const float4*)(Ab + (size_t)(id >> 4) * 4096 + ((id & 15) << 2));
    }
#pragma unroll
    for (int i = 0; i < 8; ++i) {
      int id = tid + i * 256;
      br[i] = *(const float4*)(Bb + (size_t)(id >> 4) * 4096 + ((id & 15) << 2));
    }
  };

  issue(0);
  for (int st = 0; st < KSTEPS; ++st) {
    // convert + LDS write (compiler inserts vmcnt waits on ar/br)
#pragma unroll
    for (int i = 0; i < 4; ++i) {
      int id = tid + i * 256, row = id >> 4, c4 = (id & 15) << 2;
      s16x4 h = { f2bf(ar[i].x), f2bf(ar[i].y), f2bf(ar[i].z), f2bf(ar[i].w) };
      *(s16x4*)&As[row * 72 + c4] = h;
    }
#pragma unroll
    for (int i = 0; i < 8; ++i) {
      int id = tid + i * 256, row = id >> 4, c4 = (id & 15) << 2;
      s16x4 h = { f2bf(br[i].x), f2bf(br[i].y), f2bf(br[i].z), f2bf(br[i].w) };
      *(s16x4*)&Bs[row * 72 + c4] = h;
    }
    __syncthreads();
    if (st + 1 < KSTEPS) issue(st + 1);     // prefetch next step (in flight)
    __builtin_amdgcn_sched_barrier(0);
#pragma unroll
    for (int kk = 0; kk < 64; kk += 32) {
      s16x8 a = *(const s16x8*)&As[(w * 16 + l15) * 72 + kk + l4 * 8];
#pragma unroll
      for (int nf = 0; nf < 8; ++nf) {
        s16x8 b = *(const s16x8*)&Bs[(nf * 16 + l15) * 72 + kk + l4 * 8];
        acc[nf] = mfma16(a, b, acc[nf]);
      }
    }
    __syncthreads();
  }
#pragma unroll
  for (int nf = 0; nf < 8; ++nf)
#pragma unroll
    for (int r = 0; r < 4; ++r)
      Cp[(size_t)(w * 16 + l4 * 4 + r) * ldc + nf * 16 + l15] = acc[nf][r];
}

// fused QKV: grid (48, 4, 4); cols: q 0..4095, k 4096..5119, v 5120..6143
__global__ __launch_bounds__(256, 4)
void gemm_qkv(const float* __restrict__ x,
              const float* __restrict__ wq, const float* __restrict__ wk,
              const float* __restrict__ wv, float* __restrict__ part) {
  int bn = blockIdx.x, bm = blockIdx.y, sp = blockIdx.z;
  const float* Bw;
  if (bn < 32)      Bw = wq + (size_t)(bn * 128) * 4096;
  else if (bn < 40) Bw = wk + (size_t)((bn - 32) * 128) * 4096;
  else              Bw = wv + (size_t)((bn - 40) * 128) * 4096;
  const float* A = x + (size_t)(bm * 64) * 4096 + sp * 1024;
  float* Cp = part + (size_t)sp * (256 * 6144) + (size_t)(bm * 64) * 6144 + bn * 128;
  gemm_tile<16>(A, Bw + sp * 1024, Cp, 6144);
}

// out projection: grid (32, 4, 8)
__global__ __launch_bounds__(256, 4)
void gemm_out(const float* __restrict__ y, const float* __restrict__ wo,
              float* __restrict__ part) {
  int bn = blockIdx.x, bm = blockIdx.y, sp = blockIdx.z;
  const float* A = y + (size_t)(bm * 64) * 4096 + sp * 512;
  const float* Bw = wo + (size_t)(bn * 128) * 4096 + sp * 512;
  float* Cp = part + (size_t)sp * (256 * 4096) + (size_t)(bm * 64) * 4096 + bn * 128;
  gemm_tile<8>(A, Bw, Cp, 4096);
}

// ---- qkv split-K reduce + RoPE, writes q_buf / k_new / v_new ----
__global__ __launch_bounds__(256)
void rope_reduce(const float* __restrict__ part, const float* __restrict__ ctab,
                 const float* __restrict__ stab, float* __restrict__ q,
                 float* __restrict__ kn, float* __restrict__ vn) {
  int idx = blockIdx.x * 256 + threadIdx.x;   // < 786432 = 256*3072 pairs
  int m = idx / 3072;
  int col = (idx - m * 3072) * 2;
  const float* src = part + (size_t)m * 6144 + col;
  float a0 = 0.f, a1 = 0.f;
#pragma unroll
  for (int s = 0; s < 4; ++s) {
    a0 += src[(size_t)s * 1572864];
    a1 += src[(size_t)s * 1572864 + 1];
  }
  if (col < 5120) {
    int local = (col < 4096) ? col : col - 4096;
    int f = (local & 127) >> 1, t = m & 15;
    float c = ctab[t * 64 + f], sn = stab[t * 64 + f];
    float o0 = a0 * c - a1 * sn, o1 = a0 * sn + a1 * c;
    if (col < 4096) {
      q[(size_t)m * 4096 + col] = o0;
      q[(size_t)m * 4096 + col + 1] = o1;
    } else {
      kn[(size_t)m * 1024 + local] = o0;
      kn[(size_t)m * 1024 + local + 1] = o1;
    }
  } else {
    int local = col - 5120;
    vn[(size_t)m * 1024 + local] = a0;
    vn[(size_t)m * 1024 + local + 1] = a1;
  }
}

// ---------------- flash attention with register-prefetch pipeline ----------
// grid (NS, 8, 16); 4 waves; wave w owns q-rows [w*16, w*16+16).
__global__ __launch_bounds__(256, 4)
void attn(const float* __restrict__ kc_, const float* __restrict__ vc_,
          const float* __restrict__ qb, const float* __restrict__ kn,
          const float* __restrict__ vn, const int* __restrict__ ipos,
          float* __restrict__ pO, float* __restrict__ pM, float* __restrict__ pL) {
  __shared__ short Ks[CH * 128];     // [s][d], swizzle d4 ^= (s&7)<<3
  __shared__ short Vs[128 * 40];     // [d][s], pad 40
  __shared__ short Ps[4 * 16 * 40];  // per-wave [q][s], pad 40
  const int schunks = (SEQ / CH) / NS;   // 32
  const int sh = blockIdx.x, g = blockIdx.y, b = blockIdx.z;
  const int tid = threadIdx.x, lane = tid & 63, w = tid >> 6;
  const int l15 = lane & 15, l4 = lane >> 4;
  const float scale = 0.08838834764831845f;  // 1/sqrt(128)

  const float* kc_b = kc_ + ((size_t)b * SEQ) * 1024 + g * 128;
  const float* vc_b = vc_ + ((size_t)b * SEQ) * 1024 + g * 128;
  const float* kn_b = kn + (size_t)b * 16 * 1024 + g * 128;
  const float* vn_b = vn + (size_t)b * 16 * 1024 + g * 128;

  // Q fragments
  s16x8 qa[4];
  {
    int qr = w * 16 + l15;
    int t = qr >> 2, r = qr & 3, h = g * 4 + r;
    const float* qp = qb + (size_t)(b * 16 + t) * 4096 + h * 128;
#pragma unroll
    for (int ks = 0; ks < 4; ++ks) {
      float4 v0 = *(const float4*)(qp + ks * 32 + l4 * 8);
      float4 v1 = *(const float4*)(qp + ks * 32 + l4 * 8 + 4);
      qa[ks] = s16x8{ f2bf(v0.x), f2bf(v0.y), f2bf(v0.z), f2bf(v0.w),
                      f2bf(v1.x), f2bf(v1.y), f2bf(v1.z), f2bf(v1.w) };
    }
  }
  int ip[4];
#pragma unroll
  for (int r = 0; r < 4; ++r) ip[r] = ipos[(w * 16 + l4 * 4 + r) >> 2];

  f32x4 o[8] = {};
  float mrun[4] = { -1e30f, -1e30f, -1e30f, -1e30f };
  float lrun[4] = { 0.f, 0.f, 0.f, 0.f };

  float4 kr[4];
  float vr[16];
  auto issue = [&](int base) {
    if (base + CH <= NEWBASE) {
#pragma unroll
      for (int i = 0; i < 4; ++i) {
        int id = tid + i * 256;                 // 0..1023
        int s = id >> 5, d4 = (id & 31) << 2;
        kr[i] = *(const float4*)(kc_b + (size_t)(base + s) * 1024 + d4);
      }
#pragma unroll
      for (int i = 0; i < 4; ++i) {
        int id = tid + i * 256;
        int d = id & 127, s0 = (id >> 7) << 2;
        const float* vp = vc_b + (size_t)(base + s0) * 1024 + d;
#pragma unroll
        for (int j = 0; j < 4; ++j) vr[i * 4 + j] = vp[(size_t)j * 1024];
      }
    } else {
#pragma unroll
      for (int i = 0; i < 4; ++i) {
        int id = tid + i * 256;
        int s = id >> 5, d4 = (id & 31) << 2;
        int sg = base + s;
        const float* src = (sg >= NEWBASE)
            ? (kn_b + (size_t)(sg - NEWBASE) * 1024 + d4)
            : (kc_b + (size_t)sg * 1024 + d4);
        kr[i] = *(const float4*)src;
      }
#pragma unroll
      for (int i = 0; i < 4; ++i) {
        int id = tid + i * 256;
        int d = id & 127, s0 = (id >> 7) << 2;
#pragma unroll
        for (int j = 0; j < 4; ++j) {
          int sg = base + s0 + j;
          const float* src = (sg >= NEWBASE)
              ? (vn_b + (size_t)(sg - NEWBASE) * 1024 + d)
              : (vc_b + (size_t)sg * 1024 + d);
          vr[i * 4 + j] = *src;
        }
      }
    }
  };

  issue(sh * schunks * CH);
  for (int cs = 0; cs < schunks; ++cs) {
    const int base = (sh * schunks + cs) * CH;
    // ---- convert + LDS write of chunk cs (waits on in-flight loads) ----
#pragma unroll
    for (int i = 0; i < 4; ++i) {
      int id = tid + i * 256;
      int s = id >> 5, d4 = (id & 31) << 2;
      s16x4 hv = { f2bf(kr[i].x), f2bf(kr[i].y), f2bf(kr[i].z), f2bf(kr[i].w) };
      *(s16x4*)&Ks[s * 128 + (d4 ^ ((s & 7) << 3))] = hv;
    }
#pragma unroll
    for (int i = 0; i < 4; ++i) {
      int id = tid + i * 256;
      int d = id & 127, s0 = (id >> 7) << 2;
      s16x4 hv = { f2bf(vr[i * 4]), f2bf(vr[i * 4 + 1]),
                   f2bf(vr[i * 4 + 2]), f2bf(vr[i * 4 + 3]) };
      *(s16x4*)&Vs[d * 40 + s0] = hv;
    }
    __syncthreads();
    if (cs + 1 < schunks) issue(base + CH);   // prefetch next chunk
    __builtin_amdgcn_sched_barrier(0);
    // ---- QK^T ----
    f32x4 sc[2] = {};
#pragma unroll
    for (int ks = 0; ks < 4; ++ks) {
      int dd = ks * 32 + l4 * 8;
#pragma unroll
      for (int nf = 0; nf < 2; ++nf) {
        int s = nf * 16 + l15;
        s16x8 kb = *(const s16x8*)&Ks[s * 128 + (dd ^ ((s & 7) << 3))];
        sc[nf] = mfma16(qa[ks], kb, sc[nf]);
      }
    }
    // ---- online softmax ----
    float cmax[4] = { -1e30f, -1e30f, -1e30f, -1e30f };
#pragma unroll
    for (int nf = 0; nf < 2; ++nf) {
      int sg = base + nf * 16 + l15;
#pragma unroll
      for (int r = 0; r < 4; ++r) {
        float v = sc[nf][r] * scale;
        v = (sg <= ip[r]) ? v : -1e30f;
        sc[nf][r] = v;
        cmax[r] = fmaxf(cmax[r], v);
      }
    }
#pragma unroll
    for (int r = 0; r < 4; ++r) {
      cmax[r] = fmaxf(cmax[r], __shfl_xor(cmax[r], 1, 64));
      cmax[r] = fmaxf(cmax[r], __shfl_xor(cmax[r], 2, 64));
      cmax[r] = fmaxf(cmax[r], __shfl_xor(cmax[r], 4, 64));
      cmax[r] = fmaxf(cmax[r], __shfl_xor(cmax[r], 8, 64));
    }
    bool grow = (cmax[0] > mrun[0]) | (cmax[1] > mrun[1]) |
                (cmax[2] > mrun[2]) | (cmax[3] > mrun[3]);
    if (__any(grow)) {
#pragma unroll
      for (int r = 0; r < 4; ++r) {
        float mn = fmaxf(mrun[r], cmax[r]);
        float cf = __expf(mrun[r] - mn);
        mrun[r] = mn;
        lrun[r] *= cf;
#pragma unroll
        for (int nd = 0; nd < 8; ++nd) o[nd][r] *= cf;
      }
    }
    // ---- P = exp(s - m) -> bf16 into per-wave Ps, rowsum ----
    short* Pw = &Ps[w * (16 * 40)];
    float rsum[4] = { 0.f, 0.f, 0.f, 0.f };
#pragma unroll
    for (int nf = 0; nf < 2; ++nf) {
#pragma unroll
      for (int r = 0; r < 4; ++r) {
        float p = __expf(sc[nf][r] - mrun[r]);
        rsum[r] += p;
        Pw[(l4 * 4 + r) * 40 + nf * 16 + l15] = f2bf(p);
      }
    }
#pragma unroll
    for (int r = 0; r < 4; ++r) {
      rsum[r] += __shfl_xor(rsum[r], 1, 64);
      rsum[r] += __shfl_xor(rsum[r], 2, 64);
      rsum[r] += __shfl_xor(rsum[r], 4, 64);
      rsum[r] += __shfl_xor(rsum[r], 8, 64);
      lrun[r] += rsum[r];
    }
    // ---- PV ----
    s16x8 pa = *(const s16x8*)&Pw[l15 * 40 + l4 * 8];
#pragma unroll
    for (int nd = 0; nd < 8; ++nd) {
      int d = nd * 16 + l15;
      s16x8 vb = *(const s16x8*)&Vs[d * 40 + l4 * 8];
      o[nd] = mfma16(pa, vb, o[nd]);
    }
    __syncthreads();
  }
  // ---- write partials ----
  const int blk = (b * 8 + g) * NS + sh;
  float* Ob = pO + (size_t)blk * 64 * 128;
#pragma unroll
  for (int nd = 0; nd < 8; ++nd)
#pragma unroll
    for (int r = 0; r < 4; ++r)
      Ob[(w * 16 + l4 * 4 + r) * 128 + nd * 16 + l15] = o[nd][r];
  if (l15 == 0) {
#pragma unroll
    for (int r = 0; r < 4; ++r) {
      pM[blk * 64 + w * 16 + l4 * 4 + r] = mrun[r];
      pL[blk * 64 + w * 16 + l4 * 4 + r] = lrun[r];
    }
  }
}

// ---------------- merge the NS s-splits, write y[b*16+t][h*128+d] ----------
__global__ __launch_bounds__(256)
void merge(const float* __restrict__ pO, const float* __restrict__ pM,
           const float* __restrict__ pL, float* __restrict__ y) {
  const int g = blockIdx.x, b = blockIdx.y;
  const int bb = (b * 8 + g) * NS;
#pragma unroll 4
  for (int i = 0; i < 32; ++i) {
    int id = threadIdx.x + i * 256;     // 0..8191
    int qr = id >> 7, d = id & 127;
    float M = -1e30f;
    for (int p = 0; p < NS; ++p) M = fmaxf(M, pM[(bb + p) * 64 + qr]);
    float acc = 0.f, den = 0.f;
    for (int p = 0; p < NS; ++p) {
      float a = __expf(pM[(bb + p) * 64 + qr] - M);
      acc += pO[(size_t)(bb + p) * 8192 + id] * a;
      den += pL[(bb + p) * 64 + qr] * a;
    }
    int t = qr >> 2, r = qr & 3, h = g * 4 + r;
    y[(size_t)(b * 16 + t) * 4096 + h * 128 + d] = acc / den;
  }
}

// ---- out-proj split-K reduce ----
__global__ __launch_bounds__(256)
void out_reduce(const float* __restrict__ part, float* __restrict__ out) {
  int i = blockIdx.x * 256 + threadIdx.x;   // < 262144 float4s
  const f32x4* p4 = (const f32x4*)part;
  f32x4 s = {0.f, 0.f, 0.f, 0.f};
#pragma unroll
  for (int sp = 0; sp < 8; ++sp) s += p4[(size_t)sp * 262144 + i];
  ((f32x4*)out)[i] = s;
}

extern "C" void kernel_launch(void* const* d_in, const int* in_sizes, int n_in,
                              void* d_out, int out_size, void* d_ws, size_t ws_size,
                              hipStream_t stream) {
  const float* x      = (const float*)d_in[0];
  const int*   ipos   = (const int*)d_in[3];
  const float* kcache = (const float*)d_in[5];
  const float* vcache = (const float*)d_in[6];
  const float* wq     = (const float*)d_in[7];
  const float* wk     = (const float*)d_in[8];
  const float* wv     = (const float*)d_in[9];
  const float* wo     = (const float*)d_in[10];
  float* out = (float*)d_out;

  float* q_buf = (float*)d_ws;            // 1048576
  float* k_new = q_buf + 1048576;         // 262144
  float* v_new = k_new + 262144;          // 262144
  float* y_buf = v_new + 262144;          // 1048576
  float* ctab  = y_buf + 1048576;         // 1024
  float* stab  = ctab + 1024;             // 1024
  float* pO    = stab + 1024;             // 8388608 (1024 * 64 * 128)
  float* pM    = pO + 8388608;            // 65536
  float* pL    = pM + 65536;              // 65536   total ~44.6 MB
  float* qkvp  = pO;  // alias: qkv partials (6.29M) dead before attn writes pO
  float* outp  = pO;  // alias: out partials (8.39M) live only after merge

  rope_table<<<16, 64, 0, stream>>>(ipos, ctab, stab);
  gemm_qkv<<<dim3(48, 4, 4), 256, 0, stream>>>(x, wq, wk, wv, qkvp);
  rope_reduce<<<3072, 256, 0, stream>>>(qkvp, ctab, stab, q_buf, k_new, v_new);
  attn<<<dim3(NS, 8, 16), 256, 0, stream>>>(kcache, vcache, q_buf, k_new, v_new,
                                            ipos, pO, pM, pL);
  merge<<<dim3(8, 16), 256, 0, stream>>>(pO, pM, pL, y_buf);
  gemm_out<<<dim3(32, 4, 8), 256, 0, stream>>>(y_buf, wo, outp);
  out_reduce<<<1024, 256, 0, stream>>>(outp, out);
}